// Round 7
// baseline (265.687 us; speedup 1.0000x reference)
//
#include <hip/hip_runtime.h>

// ---------------- helpers ----------------
__device__ __forceinline__ unsigned short f2bf(float f) {
    union { float f; unsigned u; } v; v.f = f;
    unsigned u = v.u;
    unsigned r = (u + 0x7fffu + ((u >> 16) & 1u)) >> 16;
    return (unsigned short)r;
}
__device__ __forceinline__ float bfup(int x) {
    union { unsigned u; float f; } v; v.u = ((unsigned)(unsigned short)x) << 16; return v.f;
}

typedef __attribute__((ext_vector_type(8))) short short8;
typedef __attribute__((ext_vector_type(4))) float floatx4;

// dims
#define Bn 4
#define Ln 256
#define Hn 768
#define Tn 16

// ---------------- K1: LayerNorm over H (fp32 in/out) ----------------
__global__ __launch_bounds__(256) void k_ln0(const float* __restrict__ x,
                                             const float* __restrict__ g,
                                             const float* __restrict__ be,
                                             float* __restrict__ out) {
    int row = blockIdx.x, tid = threadIdx.x;
    const float* xr = x + (size_t)row * Hn;
    float v0 = xr[tid], v1 = xr[tid + 256], v2 = xr[tid + 512];
    float s = v0 + v1 + v2;
    float q = v0 * v0 + v1 * v1 + v2 * v2;
    __shared__ float sm[4], qm[4];
    for (int o = 32; o > 0; o >>= 1) { s += __shfl_down(s, o); q += __shfl_down(q, o); }
    if ((tid & 63) == 0) { sm[tid >> 6] = s; qm[tid >> 6] = q; }
    __syncthreads();
    float S = sm[0] + sm[1] + sm[2] + sm[3];
    float Q = qm[0] + qm[1] + qm[2] + qm[3];
    float mean = S * (1.f / 768.f);
    float rstd = rsqrtf(Q * (1.f / 768.f) - mean * mean + 1e-5f);
    float* o0 = out + (size_t)row * Hn;
    o0[tid]       = (v0 - mean) * rstd * g[tid]       + be[tid];
    o0[tid + 256] = (v1 - mean) * rstd * g[tid + 256] + be[tid + 256];
    o0[tid + 512] = (v2 - mean) * rstd * g[tid + 512] + be[tid + 512];
}

// ---------------- K2: span means -> xv[64][1568]; also zero nf row ----------
__global__ __launch_bounds__(256) void k_spans(const float* __restrict__ emb,
                                               const int* __restrict__ ast_, const int* __restrict__ aed_,
                                               const int* __restrict__ ost_, const int* __restrict__ oed_,
                                               const int* __restrict__ sid_,
                                               float* __restrict__ xv,
                                               float* __restrict__ nf) {
    int n = blockIdx.x, b = n >> 4, tid = threadIdx.x;
    int ast = ast_[n], aed = aed_[n], ost = ost_[n], oed = oed_[n], sid = sid_[n];
    float ai = 1.f / (float)(aed - ast + 1);
    float oi = 1.f / (float)(oed - ost + 1);
    const float* eb = emb + (size_t)b * Ln * Hn;
    float* xr = xv + (size_t)n * 1568;
    for (int r = tid; r < 1568; r += 256) {
        float v;
        if (r < 768) {
            float s = 0.f;
            for (int l = ast; l <= aed; ++l) s += eb[l * Hn + r];
            v = s * ai;
        } else if (r < 1536) {
            int h = r - 768;
            float s = 0.f;
            for (int l = ost; l <= oed; ++l) s += eb[l * Hn + h];
            v = s * oi;
        } else if (r < 1539) {
            v = (sid - 2 == r - 1536) ? 1.f : 0.f;
        } else {
            v = 0.f;
        }
        xr[r] = v;
    }
    float* nr = nf + (size_t)n * Hn;
    nr[tid] = 0.f; nr[tid + 256] = 0.f; nr[tid + 512] = 0.f;
}

// ---------------- split-K skinny GEMM: C[M x 768] += A[M x Kpad] @ B[Kb x 768]
__global__ __launch_bounds__(256) void k_skinny(const float* __restrict__ A,
                                                const float* __restrict__ B,
                                                const float* __restrict__ bias,
                                                float* __restrict__ C,
                                                int Kpad, int Kb, int Kc) {
    __shared__ float At[32][33], Bt[32][33];
    int tid = threadIdx.x;
    int n0 = blockIdx.x * 32, m0 = blockIdx.y * 32, z = blockIdx.z;
    int kbeg = z * Kc;
    int kend = kbeg + Kc; if (kend > Kpad) kend = Kpad;
    int lr = tid >> 3, lc = (tid & 7) * 4;
    int tm = tid >> 3, tn4 = (tid & 7) * 4;
    float acc0 = 0.f, acc1 = 0.f, acc2 = 0.f, acc3 = 0.f;
    for (int k0 = kbeg; k0 < kend; k0 += 32) {
        float4 av = *(const float4*)(A + (size_t)(m0 + lr) * Kpad + k0 + lc);
        At[lr][lc] = av.x; At[lr][lc + 1] = av.y; At[lr][lc + 2] = av.z; At[lr][lc + 3] = av.w;
        int gk = k0 + lr;
        float4 bv = {0.f, 0.f, 0.f, 0.f};
        if (gk < Kb) bv = *(const float4*)(B + (size_t)gk * 768 + n0 + lc);
        Bt[lr][lc] = bv.x; Bt[lr][lc + 1] = bv.y; Bt[lr][lc + 2] = bv.z; Bt[lr][lc + 3] = bv.w;
        __syncthreads();
#pragma unroll
        for (int k = 0; k < 32; ++k) {
            float a = At[tm][k];
            acc0 = fmaf(a, Bt[k][tn4], acc0);
            acc1 = fmaf(a, Bt[k][tn4 + 1], acc1);
            acc2 = fmaf(a, Bt[k][tn4 + 2], acc2);
            acc3 = fmaf(a, Bt[k][tn4 + 3], acc3);
        }
        __syncthreads();
    }
    if (z == 0) {
        acc0 += bias[n0 + tn4];
        acc1 += bias[n0 + tn4 + 1];
        acc2 += bias[n0 + tn4 + 2];
        acc3 += bias[n0 + tn4 + 3];
    }
    float* dst = C + (size_t)(m0 + tm) * 768 + n0 + tn4;
    atomicAdd(&dst[0], acc0);
    atomicAdd(&dst[1], acc1);
    atomicAdd(&dst[2], acc2);
    atomicAdd(&dst[3], acc3);
}

// ---------------- K4: graph attention + aggregation (LDS-staged) ----------------
__global__ __launch_bounds__(256) void k_graph(const float* __restrict__ nf,
                                               const int* __restrict__ ast_, const int* __restrict__ aed_,
                                               const int* __restrict__ ost_, const int* __restrict__ oed_,
                                               const float* __restrict__ E,
                                               const float* __restrict__ Wat,
                                               const float* __restrict__ bat,
                                               int* __restrict__ hasin, float* __restrict__ hasedge,
                                               float* __restrict__ agg, float* __restrict__ raw) {
    int b = blockIdx.x, tid = threadIdx.x;
    __shared__ float nfs[16][780];
    __shared__ float Es[2][768];
    __shared__ int ast[16], aed[16], ost[16], oed[16];
    __shared__ float red[256];
    __shared__ float nrm[16], p[16], q[16], rr[2];
    __shared__ float ws2[16][16];
    __shared__ float aes[16][2];
    __shared__ unsigned m0b[16], m1b[16];
    const float* nfb = nf + (size_t)b * 16 * Hn;
    for (int e = tid; e < 3072; e += 256) {
        int r = e / 192, c = (e - r * 192) * 4;
        float4 v = *(const float4*)(nfb + r * Hn + c);
        nfs[r][c] = v.x; nfs[r][c + 1] = v.y; nfs[r][c + 2] = v.z; nfs[r][c + 3] = v.w;
    }
    for (int e = tid; e < 1536; e += 256) ((float*)Es)[e] = E[e];
    if (tid < 16) {
        int n = b * 16 + tid;
        ast[tid] = ast_[n]; aed[tid] = aed_[n]; ost[tid] = ost_[n]; oed[tid] = oed_[n];
        m0b[tid] = 0u; m1b[tid] = 0u;
    }
    __syncthreads();
    int t = tid >> 4, lane = tid & 15;
    float ss = 0.f, pp = 0.f, qq = 0.f;
    for (int h = lane; h < 768; h += 16) {
        float v = nfs[t][h];
        ss = fmaf(v, v, ss);
        float lr = v > 0.f ? v : 0.2f * v;
        pp = fmaf(lr, Wat[h], pp);
        qq = fmaf(lr, Wat[768 + h], qq);
    }
    red[tid] = ss; __syncthreads();
    if (tid < 16) { float s = 0.f; for (int k2 = 0; k2 < 16; ++k2) s += red[tid * 16 + k2]; nrm[tid] = sqrtf(s); }
    __syncthreads();
    red[tid] = pp; __syncthreads();
    if (tid < 16) { float s = 0.f; for (int k2 = 0; k2 < 16; ++k2) s += red[tid * 16 + k2]; p[tid] = s; }
    __syncthreads();
    red[tid] = qq; __syncthreads();
    if (tid < 16) { float s = 0.f; for (int k2 = 0; k2 < 16; ++k2) s += red[tid * 16 + k2]; q[tid] = s; }
    __syncthreads();
    float rp = 0.f;
    if (tid < 32) {
        int e = tid >> 4;
        for (int h = lane; h < 768; h += 16) {
            float v = Es[e][h];
            float lr = v > 0.f ? v : 0.2f * v;
            rp = fmaf(lr, Wat[1536 + h], rp);
        }
    }
    red[tid] = rp; __syncthreads();
    if (tid < 2) { float s = 0.f; for (int k2 = 0; k2 < 16; ++k2) s += red[tid * 16 + k2]; rr[tid] = s; }
    __syncthreads();
    // cosine sim (float4 LDS reads), edge masks
    {
        int i = tid >> 4, j = tid & 15;
        const float4* ri = (const float4*)nfs[i];
        const float4* rj = (const float4*)nfs[j];
        float dot = 0.f;
#pragma unroll 4
        for (int h4 = 0; h4 < 192; ++h4) {
            float4 a = ri[h4], c = rj[h4];
            dot = fmaf(a.x, c.x, dot); dot = fmaf(a.y, c.y, dot);
            dot = fmaf(a.z, c.z, dot); dot = fmaf(a.w, c.w, dot);
        }
        float sim = dot / (fmaxf(nrm[i], 1e-8f) * fmaxf(nrm[j], 1e-8f));
        bool ok = (sim > 0.f) && (i != j);
        if (ok && ast[i] == ast[j] && aed[i] == aed[j]) atomicOr(&m0b[i], 1u << j);
        if (ok && ost[i] == ost[j] && oed[i] == oed[j]) atomicOr(&m1b[i], 1u << j);
    }
    __syncthreads();
    if (tid < 16) {
        int tt = tid;
        float battn = bat[0];
        float sc[32];
        float mx = -3.4e38f;
        bool hi = false;
#pragma unroll
        for (int s = 0; s < 16; ++s) {
            bool e0 = (m0b[s] >> tt) & 1u;   // emask[t,s,0] = m0[s,t]
            bool e1 = (m1b[s] >> tt) & 1u;
            float base = p[tt] + q[s] + battn;
            float v0 = e0 ? (base + rr[0]) : -1e9f;
            float v1 = e1 ? (base + rr[1]) : -1e9f;
            sc[2 * s] = v0; sc[2 * s + 1] = v1;
            mx = fmaxf(mx, fmaxf(v0, v1));
            hi = hi || e0 || e1;
        }
        float sum = 0.f;
#pragma unroll
        for (int k2 = 0; k2 < 32; ++k2) { float e = expf(sc[k2] - mx); sc[k2] = e; sum += e; }
        float inv = 1.f / sum;
        float ae0 = 0.f, ae1 = 0.f;
#pragma unroll
        for (int s = 0; s < 16; ++s) {
            float w0 = sc[2 * s] * inv, w1 = sc[2 * s + 1] * inv;
            ws2[tt][s] = w0 + w1;
            ae0 += w0; ae1 += w1;
        }
        aes[tt][0] = ae0; aes[tt][1] = ae1;
        hasin[b * 16 + tt] = hi ? 1 : 0;
        red[tid] = hi ? 1.f : 0.f;
    }
    __syncthreads();
    if (tid == 0) {
        float he = 0.f;
        for (int k2 = 0; k2 < 16; ++k2) he = fmaxf(he, red[k2]);
        hasedge[b] = he;
    }
    // aggregation for this block's 16 nodes (+ zero raw rows for skinny2 atomics)
    for (int nn = 0; nn < 16; ++nn) {
        int n = b * 16 + nn;
        float ae0 = aes[nn][0], ae1 = aes[nn][1];
        float* ag = agg + (size_t)n * 1536;
        float* rw = raw + (size_t)n * Hn;
        for (int f = tid; f < 768; f += 256) {
            float s = 0.f;
#pragma unroll
            for (int s16 = 0; s16 < 16; ++s16) s = fmaf(ws2[nn][s16], nfs[s16][f], s);
            ag[f] = s;
            ag[768 + f] = ae0 * Es[0][f] + ae1 * Es[1][f];
            rw[f] = 0.f;
        }
    }
}

// ---------------- K5b: select + scatter-add into emb ----------------
__global__ __launch_bounds__(256) void k_scatter(const float* __restrict__ raw,
                                                 const float* __restrict__ nf,
                                                 const int* __restrict__ hasin, const float* __restrict__ hasedge,
                                                 const int* __restrict__ ast_, const int* __restrict__ ost_,
                                                 float* __restrict__ emb) {
    int n = blockIdx.x, b = n >> 4, tid = threadIdx.x;
    if (hasedge[b] == 0.f) return;
    int center = (ast_[n] + ost_[n]) >> 1;
    float* dst = emb + (size_t)(b * Ln + center) * Hn;
    int hi = hasin[n];
    const float* src = hi ? (raw + (size_t)n * Hn) : (nf + (size_t)n * Hn);
    for (int h = tid; h < 768; h += 256) {
        float v = src[h];
        if (hi) v = fmaxf(v, 0.f);
        atomicAdd(&dst[h], v);
    }
}

// ---------------- K6b: W1[1536][256] fp32 -> w1t[512][768] bf16 (B^T) ----------
__global__ __launch_bounds__(256) void k_w1t(const float* __restrict__ W1,
                                             unsigned short* __restrict__ w1t) {
    __shared__ float tile[32][33];
    int kt = blockIdx.x, nt = blockIdx.y, tid = threadIdx.x;
    int k0 = kt * 32, n0 = nt * 32;
    int rowoff = (n0 < 256) ? 0 : 768;
    int col0 = n0 & 255;
    int r = tid >> 3, c = (tid & 7) * 4;
    float4 v = *(const float4*)(W1 + (size_t)(rowoff + k0 + r) * 256 + col0 + c);
    tile[r][c] = v.x; tile[r][c + 1] = v.y; tile[r][c + 2] = v.z; tile[r][c + 3] = v.w;
    __syncthreads();
    ushort4 o;
    o.x = f2bf(tile[c][r]); o.y = f2bf(tile[c + 1][r]);
    o.z = f2bf(tile[c + 2][r]); o.w = f2bf(tile[c + 3][r]);
    *(ushort4*)(w1t + (size_t)(n0 + r) * 768 + k0 + c) = o;
}

// ---------------- K7: MFMA GEMM  abm[1024][512] = bf16(emb) @ w1t^T (inline cvt)
__global__ __launch_bounds__(64) void k_gemm(const float* __restrict__ emb,
                                             const unsigned short* __restrict__ w1t,
                                             float* __restrict__ abm) {
    int wid = blockIdx.x;                 // 512 waves
    int m0 = (wid >> 4) * 32;
    int n0 = (wid & 15) * 32;
    int lane = threadIdx.x;
    int r = lane & 15, g = lane >> 4;
    const float* Af0 = emb + (size_t)(m0 + r) * 768 + g * 8;
    const float* Af1 = emb + (size_t)(m0 + 16 + r) * 768 + g * 8;
    const short8* Bp0 = (const short8*)(w1t + (size_t)(n0 + r) * 768 + g * 8);
    const short8* Bp1 = (const short8*)(w1t + (size_t)(n0 + 16 + r) * 768 + g * 8);
    floatx4 acc00 = {0.f, 0.f, 0.f, 0.f}, acc01 = {0.f, 0.f, 0.f, 0.f};
    floatx4 acc10 = {0.f, 0.f, 0.f, 0.f}, acc11 = {0.f, 0.f, 0.f, 0.f};
#pragma unroll 4
    for (int ks = 0; ks < 768; ks += 32) {
        float4 x0 = *(const float4*)(Af0 + ks);
        float4 x1 = *(const float4*)(Af0 + ks + 4);
        float4 y0 = *(const float4*)(Af1 + ks);
        float4 y1 = *(const float4*)(Af1 + ks + 4);
        short8 a0, a1;
        union { float f; unsigned u; } cv;
#define PK(dst, idx, val) { cv.f = (val); dst[idx] = (short)((cv.u + 0x8000u) >> 16); }
        PK(a0, 0, x0.x) PK(a0, 1, x0.y) PK(a0, 2, x0.z) PK(a0, 3, x0.w)
        PK(a0, 4, x1.x) PK(a0, 5, x1.y) PK(a0, 6, x1.z) PK(a0, 7, x1.w)
        PK(a1, 0, y0.x) PK(a1, 1, y0.y) PK(a1, 2, y0.z) PK(a1, 3, y0.w)
        PK(a1, 4, y1.x) PK(a1, 5, y1.y) PK(a1, 6, y1.z) PK(a1, 7, y1.w)
#undef PK
        short8 b0 = Bp0[ks >> 3];
        short8 b1 = Bp1[ks >> 3];
        acc00 = __builtin_amdgcn_mfma_f32_16x16x32_bf16(a0, b0, acc00, 0, 0, 0);
        acc01 = __builtin_amdgcn_mfma_f32_16x16x32_bf16(a0, b1, acc01, 0, 0, 0);
        acc10 = __builtin_amdgcn_mfma_f32_16x16x32_bf16(a1, b0, acc10, 0, 0, 0);
        acc11 = __builtin_amdgcn_mfma_f32_16x16x32_bf16(a1, b1, acc11, 0, 0, 0);
    }
#pragma unroll
    for (int t = 0; t < 4; ++t) {
        int row = g * 4 + t;
        abm[(size_t)(m0 + row) * 512 + n0 + r]           = acc00[t];
        abm[(size_t)(m0 + row) * 512 + n0 + 16 + r]      = acc01[t];
        abm[(size_t)(m0 + 16 + row) * 512 + n0 + r]      = acc10[t];
        abm[(size_t)(m0 + 16 + row) * 512 + n0 + 16 + r] = acc11[t];
    }
}

// ---------------- K9: per-row prep: bf16 copies + row stats ----------------
__global__ __launch_bounds__(256) void k_prep(const float* __restrict__ abm,
                                              const float* __restrict__ bl1,
                                              unsigned short* __restrict__ Abf,
                                              unsigned short* __restrict__ Bbf,
                                              float* __restrict__ sA, float* __restrict__ qA,
                                              float* __restrict__ sB, float* __restrict__ qB) {
    int rw = blockIdx.x, tid = threadIdx.x;
    float a = abm[(size_t)rw * 512 + tid];
    float bp = abm[(size_t)rw * 512 + 256 + tid] + bl1[tid];
    Abf[(size_t)rw * 256 + tid] = f2bf(a);
    Bbf[(size_t)rw * 256 + tid] = f2bf(bp);
    float v0 = a, v1 = a * a, v2 = bp, v3 = bp * bp;
    __shared__ float red[4][4];
    for (int o = 32; o > 0; o >>= 1) {
        v0 += __shfl_down(v0, o); v1 += __shfl_down(v1, o);
        v2 += __shfl_down(v2, o); v3 += __shfl_down(v3, o);
    }
    if ((tid & 63) == 0) {
        int w = tid >> 6;
        red[w][0] = v0; red[w][1] = v1; red[w][2] = v2; red[w][3] = v3;
    }
    __syncthreads();
    if (tid == 0) {
        sA[rw] = red[0][0] + red[1][0] + red[2][0] + red[3][0];
        qA[rw] = red[0][1] + red[1][1] + red[2][1] + red[3][1];
        sB[rw] = red[0][2] + red[1][2] + red[2][2] + red[3][2];
        qB[rw] = red[0][3] + red[1][3] + red[2][3] + red[3][3];
    }
}

// ---------------- K10: cross-dots D[b][i][j] = A_i . (B_j + bl1), fp32 --------
__global__ __launch_bounds__(256) void k_dots(const float* __restrict__ abm,
                                              const float* __restrict__ bl1,
                                              float* __restrict__ D) {
    __shared__ float At[32][33], Bt[32][33];
    int tid = threadIdx.x;
    int j0 = blockIdx.x * 32, i0 = blockIdx.y * 32, b = blockIdx.z;
    int lr = tid >> 3, lc = (tid & 7) * 4;
    int ti = tid >> 3, tj4 = (tid & 7) * 4;
    float acc0 = 0.f, acc1 = 0.f, acc2 = 0.f, acc3 = 0.f;
    for (int k0 = 0; k0 < 256; k0 += 32) {
        float4 av = *(const float4*)(abm + (size_t)(b * 256 + i0 + lr) * 512 + k0 + lc);
        At[lr][lc] = av.x; At[lr][lc + 1] = av.y; At[lr][lc + 2] = av.z; At[lr][lc + 3] = av.w;
        float4 bv = *(const float4*)(abm + (size_t)(b * 256 + j0 + lr) * 512 + 256 + k0 + lc);
        float4 lv = *(const float4*)(bl1 + k0 + lc);
        Bt[lr][lc] = bv.x + lv.x; Bt[lr][lc + 1] = bv.y + lv.y;
        Bt[lr][lc + 2] = bv.z + lv.z; Bt[lr][lc + 3] = bv.w + lv.w;
        __syncthreads();
#pragma unroll
        for (int k = 0; k < 32; ++k) {
            float a = At[ti][k];
            acc0 = fmaf(a, Bt[tj4][k], acc0);
            acc1 = fmaf(a, Bt[tj4 + 1][k], acc1);
            acc2 = fmaf(a, Bt[tj4 + 2][k], acc2);
            acc3 = fmaf(a, Bt[tj4 + 3][k], acc3);
        }
        __syncthreads();
    }
    float* dst = D + ((size_t)b * 256 + i0 + ti) * 256 + j0 + tj4;
    dst[0] = acc0; dst[1] = acc1; dst[2] = acc2; dst[3] = acc3;
}

// ---------------- K11: fused LN+GELU+MFMA-proj, single pass ----------------
__global__ __launch_bounds__(256) void k_hidden2(const unsigned short* __restrict__ Abf,
                                                 const unsigned short* __restrict__ Bbf,
                                                 const float* __restrict__ sA, const float* __restrict__ qA,
                                                 const float* __restrict__ sB, const float* __restrict__ qB,
                                                 const float* __restrict__ D,
                                                 const float* __restrict__ masks,
                                                 const float* __restrict__ g1, const float* __restrict__ b1,
                                                 const float* __restrict__ Wc, const float* __restrict__ bc,
                                                 const float* __restrict__ Wc1, const float* __restrict__ bc1,
                                                 float* __restrict__ out) {
    __shared__ unsigned short As[16][272];   // pitch 272 bf16 (136 dwords -> conflict-free frag reads)
    __shared__ unsigned short Bs[16][272];
    __shared__ unsigned short gsh[256], bsh[256];
    __shared__ short8 Wf[8][64];
    __shared__ float Ds[16][16];
    __shared__ float ms[16][16];
    __shared__ float sAs[16], qAs[16], sBs[16], qBs[16];
    int tid = threadIdx.x;
    int jt = blockIdx.x, it = blockIdx.y, b = blockIdx.z;
    int rowA = b * 256 + it * 16;
    int rowB = b * 256 + jt * 16;
    // stage A/B rows (16 rows x 256 bf16 each) as 512 chunks of 8 bf16
#pragma unroll
    for (int u = 0; u < 2; ++u) {
        int e = tid + u * 256;
        int r = e >> 5, ch = e & 31;
        *(short8*)&As[r][ch * 8] = *(const short8*)(Abf + (size_t)(rowA + r) * 256 + ch * 8);
        *(short8*)&Bs[r][ch * 8] = *(const short8*)(Bbf + (size_t)(rowB + r) * 256 + ch * 8);
    }
    gsh[tid] = f2bf(g1[tid]);
    bsh[tid] = f2bf(b1[tid]);
    // W fragments: Wf[s][l][t] = W[k = s*32 + (l>>4)*8 + t][n = l&15]  (n>=8 -> 0)
#pragma unroll
    for (int u = 0; u < 2; ++u) {
        int e = tid + u * 256;
        int s = e >> 6, l = e & 63;
        int qq2 = l >> 4, nn2 = l & 15;
        short8 wv;
#pragma unroll
        for (int t = 0; t < 8; ++t) {
            int k = s * 32 + qq2 * 8 + t;
            float v = (nn2 < 6) ? Wc[k * 6 + nn2] : ((nn2 < 8) ? Wc1[k * 2 + (nn2 - 6)] : 0.f);
            wv[t] = (short)f2bf(v);
        }
        Wf[s][l] = wv;
    }
    {
        int di = tid >> 4, dj = tid & 15;
        size_t gi = ((size_t)(b * 256 + it * 16 + di)) * 256 + jt * 16 + dj;
        Ds[di][dj] = D[gi];
        ms[di][dj] = masks[gi];
    }
    if (tid < 16) {
        sAs[tid] = sA[rowA + tid]; qAs[tid] = qA[rowA + tid];
        sBs[tid] = sB[rowB + tid]; qBs[tid] = qB[rowB + tid];
    }
    __syncthreads();

    int lane = tid & 63, w = tid >> 6;
    int m = lane & 15, q = lane >> 4;
    int iA = w * 4 + (m & 3);
    int n = m;
    float bcs_l = (n < 6) ? bc[n] : ((n < 8) ? bc1[n - 6] : 0.f);
    const float inv256 = 1.f / 256.f;
    const float K1 = -1.5957691216f, K2 = -0.0713548163f;

    for (int p = 0; p < 4; ++p) {
        int jB = p * 4 + (m >> 2);
        float mu = (sAs[iA] + sBs[jB]) * inv256;
        float E2 = (qAs[iA] + 2.f * Ds[iA][jB] + qBs[jB]) * inv256;
        float r_ = rsqrtf(E2 - mu * mu + 1e-5f);
        float c_ = -mu * r_;
        floatx4 acc = {0.f, 0.f, 0.f, 0.f};
#pragma unroll
        for (int s = 0; s < 8; ++s) {
            int ko = s * 32 + q * 8;
            short8 a8 = *(const short8*)&As[iA][ko];
            short8 b8 = *(const short8*)&Bs[jB][ko];
            short8 g8 = *(const short8*)&gsh[ko];
            short8 v8 = *(const short8*)&bsh[ko];
            short8 yv;
#pragma unroll
            for (int t = 0; t < 8; ++t) {
                float h = bfup(a8[t]) + bfup(b8[t]);
                float x = fmaf(h, r_, c_);
                x = fmaf(x, bfup(g8[t]), bfup(v8[t]));
                float mm = fmaf(x * x, K2, K1);
                float e = __expf(x * mm);
                float y = x * __builtin_amdgcn_rcpf(1.f + e);
                union { float f; unsigned u; } cv; cv.f = y;
                yv[t] = (short)((cv.u + 0x8000u) >> 16);
            }
            acc = __builtin_amdgcn_mfma_f32_16x16x32_bf16(yv, Wf[s][lane], acc, 0, 0, 0);
        }
        if (n < 8) {
#pragma unroll
            for (int rg = 0; rg < 4; ++rg) {
                int mp = q * 4 + rg;               // output pair index
                int il = w * 4 + (mp & 3);
                int jl = p * 4 + (mp >> 2);
                float mk = ms[il][jl];
                size_t idx = (((size_t)(b * 256 + it * 16 + il)) * 256 + jt * 16 + jl) * 8 + n;
                out[idx] = (acc[rg] + bcs_l) * mk;
            }
        }
    }
}

// ---------------- launch ----------------
extern "C" void kernel_launch(void* const* d_in, const int* in_sizes, int n_in,
                              void* d_out, int out_size, void* d_ws, size_t ws_size,
                              hipStream_t stream) {
    (void)in_sizes; (void)n_in; (void)out_size; (void)ws_size;
    const float* emb_in = (const float*)d_in[0];
    const float* masks  = (const float*)d_in[1];
    const int* ast = (const int*)d_in[2];
    const int* aed = (const int*)d_in[3];
    const int* ost = (const int*)d_in[4];
    const int* oed = (const int*)d_in[5];
    const int* sid = (const int*)d_in[6];
    const float* E    = (const float*)d_in[7];
    const float* Wtp  = (const float*)d_in[8];
    const float* btp  = (const float*)d_in[9];
    const float* Wat  = (const float*)d_in[10];
    const float* bat  = (const float*)d_in[11];
    const float* Wg   = (const float*)d_in[12];
    const float* bg   = (const float*)d_in[13];
    const float* g0   = (const float*)d_in[14];
    const float* b0   = (const float*)d_in[15];
    const float* W1   = (const float*)d_in[16];
    const float* bl1  = (const float*)d_in[17];
    const float* g1   = (const float*)d_in[18];
    const float* b1   = (const float*)d_in[19];
    const float* Wc   = (const float*)d_in[20];
    const float* bc   = (const float*)d_in[21];
    const float* Wc1  = (const float*)d_in[22];
    const float* bc1  = (const float*)d_in[23];
    float* outp = (float*)d_out;

    float* fw = (float*)d_ws;
    float* emb = fw;                                   // 786432
    float* nf  = fw + 786432;                          // 49152 -> 835584
    int*   hasin = (int*)(fw + 835584);                // 64
    float* hasedge = fw + 835648;                      // 4  (pad to 835712)
    float* xv  = fw + 835712;                          // 100352 -> 936064
    float* agg = fw + 936064;                          // 98304  -> 1034368
    float* raw = fw + 1034368;                         // 49152  -> 1083520
    float* Dd  = fw + 835712;                          // 262144 -> 1097856 (reuses xv/agg/raw; temporally disjoint)
    float* abm = fw + 1097856;                         // 524288 -> 1622144
    float* sA  = fw + 1622144;
    float* qA  = fw + 1623168;
    float* sB  = fw + 1624192;
    float* qB  = fw + 1625216;                         // -> 1626240
    unsigned short* Abf = (unsigned short*)(fw + 1626240);   // 131072 fl
    unsigned short* Bbf = (unsigned short*)(fw + 1757312);   // 131072 fl
    unsigned short* w1t = (unsigned short*)(fw + 1888384);   // 196608 fl -> 2084992

    dim3 gw(24, 16);
    k_w1t<<<gw, 256, 0, stream>>>(W1, w1t);
    k_ln0<<<1024, 256, 0, stream>>>(emb_in, g0, b0, emb);
    k_spans<<<64, 256, 0, stream>>>(emb, ast, aed, ost, oed, sid, xv, nf);
    dim3 gs1(24, 2, 7);
    k_skinny<<<gs1, 256, 0, stream>>>(xv, Wtp, btp, nf, 1568, 1539, 224);
    k_graph<<<4, 256, 0, stream>>>(nf, ast, aed, ost, oed, E, Wat, bat, hasin, hasedge, agg, raw);
    k_skinny<<<gs1, 256, 0, stream>>>(agg, Wg, bg, raw, 1536, 1536, 224);
    k_scatter<<<64, 256, 0, stream>>>(raw, nf, hasin, hasedge, ast, ost, emb);
    k_gemm<<<512, 64, 0, stream>>>(emb, w1t, abm);
    k_prep<<<1024, 256, 0, stream>>>(abm, bl1, Abf, Bbf, sA, qA, sB, qB);
    dim3 gd(8, 8, 4);
    k_dots<<<gd, 256, 0, stream>>>(abm, bl1, Dd);
    dim3 g6(16, 16, 4);
    k_hidden2<<<g6, 256, 0, stream>>>(Abf, Bbf, sA, qA, sB, qB, Dd, masks,
                                      g1, b1, Wc, bc, Wc1, bc1, outp);
}